// Round 22
// baseline (5518.961 us; speedup 1.0000x reference)
//
#include <hip/hip_runtime.h>
#include <math.h>

#define HW 65536
#define DD 160
#define NB 2
#define DCH 40
#define NSL (DCH + 6)   // 46 marched slices per chunk incl. halo
#define NCH 4
#define TW 32
#define TH 16
#define PH 23           // h-pitch (odd -> 2-way LDS access, free)

#define SSIM_C1 1e-4f
#define SSIM_C2 9e-4f

typedef float f32x2 __attribute__((ext_vector_type(2)));

struct Gw { float g[7]; };

static __device__ __forceinline__ f32x2 s2(float v) { f32x2 r; r.x = v; r.y = v; return r; }

// Fused SSIM3D v22: champion v15 machinery (depth-2 cA/cB register prefetch,
// u/v 4-field algebra, transposed packed planes, raw-load issue sites,
// multiplier masking) restructured to TWO slices per barrier: phase m does
// W(cA, slice 2m) + W(cB, slice 2m+1) -> slot pair (m&1), prefetches
// 2m+2 -> cA / 2m+3 -> cB, then H+D for slices 2m-2, 2m-1 from the other
// slot pair, ONE __syncthreads. Barriers 47 -> 25. Geometry and per-thread
// register state IDENTICAL to v15 (unlike R16, whose pairing doubled state
// and spilled at the VGPR-128 cap). Tests the barrier-fixed-cost hypothesis
// cleanly: per-phase ledger shows ~2.2us wall vs ~1.3us busy per barrier.
__global__ __launch_bounds__(256, 2) void k_fused(
    const float* __restrict__ img1, const float* __restrict__ img2,
    Gw gw, float* __restrict__ partials)
{
    __shared__ f32x2 pUV[4][TW][PH];   // 2 slot-pairs x (conv_w u, conv_w v)
    __shared__ f32x2 pSQ[4][TW][PH];   // 2 slot-pairs x (conv_w u^2, conv_w v^2)
    __shared__ float red[256];

    const int tid = threadIdx.x;
    const int nb = blockIdx.z >> 2;
    const int o0 = (blockIdx.z & 3) * DCH;
    const int h0 = blockIdx.y * TH;
    const int w0 = blockIdx.x * TW;
    const float* i1 = img1 + (size_t)nb * DD * HW;
    const float* i2 = img2 + (size_t)nb * DD * HW;

    // ---- W-thread geometry (tid < 176): row hh (0..21), 4 outputs at wb ----
    const bool wth = (tid < 176);
    const int hh = tid >> 3;
    const int wb = (tid & 7) * 4;
    const int gh = h0 - 3 + hh;
    const int gwb = w0 - 3 + wb;
    const bool ghv = wth && ((unsigned)gh < 256u);
    const int ghc = gh < 0 ? 0 : (gh > 255 ? 255 : gh);
    int coff[10];
    float mx[10];
#pragma unroll
    for (int i = 0; i < 10; ++i) {
        int gwi = gwb + i;
        int gc = gwi < 0 ? 0 : (gwi > 255 ? 255 : gwi);
        coff[i] = ghc * 256 + gc;                      // always-in-bounds address
        mx[i] = (ghv && gwi == gc) ? 1.f : 0.f;        // zero-pad multiplier
    }

    // ---- H/D geometry: all 256 threads, 2 output rows each ----
    const int wcol = tid & 31;
    const int hb = (tid >> 5) * 2;   // 0..14

    f32x2 ringUV[2][7] = {};
    f32x2 ringSQ[2][7] = {};
    float lsum = 0.f;
    f32x2 cA[10], cB[10];   // ping-pong slice buffers (raw x,y)

    // raw slice loader: 20 independent loads, NO dependent VALU at issue site
    auto LOADTO = [&](f32x2 (&buf)[10], int s) {
        const float* p1 = i1 + (size_t)s * HW;
        const float* p2 = i2 + (size_t)s * HW;
#pragma unroll
        for (int i = 0; i < 10; ++i) buf[i].x = p1[coff[i]];
#pragma unroll
        for (int i = 0; i < 10; ++i) buf[i].y = p2[coff[i]];
    };

    // prologue: slice r=0 -> cA, slice r=1 -> cB (skipped if out of range;
    // W for those r is also skipped, so buffer contents don't matter)
    {
        const int s0 = o0 - 3;
        if (s0 >= 0 && wth) LOADTO(cA, s0);
        const int s1 = o0 - 2;
        if (s1 >= 0 && s1 < DD && wth) LOADTO(cB, s1);
    }

#define WPASS(CUR, SLOT)                                                      \
    {                                                                         \
        f32x2 aUV[4] = {};                                                    \
        f32x2 aSQ[4] = {};                                                    \
        _Pragma("unroll")                                                     \
        for (int i = 0; i < 10; ++i) {                                        \
            f32x2 uv;                                                         \
            uv.x = CUR[i].x + CUR[i].y;                                       \
            uv.y = CUR[i].x - CUR[i].y;                                       \
            uv = uv * s2(mx[i]);                                              \
            const f32x2 sq = uv * uv;                                         \
            _Pragma("unroll")                                                 \
            for (int o = 0; o < 4; ++o) {                                     \
                const int k = i - o;                                          \
                if (k >= 0 && k < 7) {                                        \
                    const float gk = gw.g[k];                                 \
                    aUV[o] += s2(gk) * uv;                                    \
                    aSQ[o] += s2(gk) * sq;                                    \
                }                                                             \
            }                                                                 \
        }                                                                     \
        _Pragma("unroll")                                                     \
        for (int o = 0; o < 4; ++o) {                                         \
            pUV[SLOT][wb + o][hh] = aUV[o];                                   \
            pSQ[SLOT][wb + o][hh] = aSQ[o];                                   \
        }                                                                     \
    }

#define HD(RP, RI, SLOT)                                                      \
    {                                                                         \
        const int rp_ = (RP);                                                 \
        if (rp_ >= 0 && rp_ < NSL) {                                          \
            const int sp_ = o0 - 3 + rp_;                                     \
            if (sp_ >= 0 && sp_ < DD) {                                       \
                f32x2 vU[8], vS[8];                                           \
                _Pragma("unroll")                                             \
                for (int i = 0; i < 8; ++i) {                                 \
                    vU[i] = pUV[SLOT][wcol][hb + i];                          \
                    vS[i] = pSQ[SLOT][wcol][hb + i];                          \
                }                                                             \
                _Pragma("unroll")                                             \
                for (int o = 0; o < 2; ++o) {                                 \
                    f32x2 aU = s2(0.f), aS = s2(0.f);                         \
                    _Pragma("unroll")                                         \
                    for (int k = 0; k < 7; ++k) {                             \
                        const float gk = gw.g[k];                             \
                        aU += s2(gk) * vU[o + k];                             \
                        aS += s2(gk) * vS[o + k];                             \
                    }                                                         \
                    ringUV[o][RI] = aU;                                       \
                    ringSQ[o][RI] = aS;                                       \
                }                                                             \
            } else {                                                          \
                _Pragma("unroll")                                             \
                for (int o = 0; o < 2; ++o) {                                 \
                    ringUV[o][RI] = s2(0.f);                                  \
                    ringSQ[o][RI] = s2(0.f);                                  \
                }                                                             \
            }                                                                 \
            if (rp_ >= 6) {                                                   \
                _Pragma("unroll")                                             \
                for (int o = 0; o < 2; ++o) {                                 \
                    f32x2 cU = s2(0.f), cS = s2(0.f);                         \
                    _Pragma("unroll")                                         \
                    for (int k = 0; k < 7; ++k) {                             \
                        const float gk = gw.g[k];                             \
                        const int pp = ((RI) + 1 + k) % 7;                    \
                        cU += s2(gk) * ringUV[o][pp];                         \
                        cS += s2(gk) * ringSQ[o][pp];                         \
                    }                                                         \
                    /* A=conv(u), B=conv(v), P=conv(u^2), Q=conv(v^2) */      \
                    const f32x2 ab2 = cU * cU;                                \
                    const float sAB = ab2.x + ab2.y;                          \
                    const float dAB = ab2.x - ab2.y;                          \
                    const float sPQ = cS.x + cS.y;                            \
                    const float dPQ = cS.x - cS.y;                            \
                    const float num1 = 0.5f * dAB + SSIM_C1;                  \
                    const float num2 = 0.5f * (dPQ - dAB) + SSIM_C2;          \
                    const float den1 = 0.5f * sAB + SSIM_C1;                  \
                    const float den2 = 0.5f * (sPQ - sAB) + SSIM_C2;          \
                    lsum += (num1 * num2) *                                   \
                            __builtin_amdgcn_rcpf(den1 * den2);               \
                }                                                             \
            }                                                                 \
        }                                                                     \
    }

#define PAIR(J)                                                               \
    {                                                                         \
        const int m = 14 * t2 + (J);                                          \
        if (m <= 23) {                                                        \
            const int r0 = 2 * m;                                             \
            const int s0c = o0 - 3 + r0;                                      \
            /* 1) W-pass slice 2m (cA) and 2m+1 (cB) -> slot pair (J&1) */    \
            if (wth && (r0 < NSL) && (s0c >= 0) && (s0c < DD))                \
                WPASS(cA, ((J) & 1) * 2)                                      \
            if (wth && (r0 + 1 < NSL) && (s0c + 1 >= 0) && (s0c + 1 < DD))    \
                WPASS(cB, ((J) & 1) * 2 + 1)                                  \
            /* 2) prefetch pair m+1: slices 2m+2 -> cA, 2m+3 -> cB */         \
            if (wth && (r0 + 2 < NSL) && (s0c + 2 >= 0) && (s0c + 2 < DD))    \
                LOADTO(cA, s0c + 2);                                          \
            if (wth && (r0 + 3 < NSL) && (s0c + 3 >= 0) && (s0c + 3 < DD))    \
                LOADTO(cB, s0c + 3);                                          \
            /* 3) H+D for slices 2m-2, 2m-1 from the other slot pair */       \
            HD(r0 - 2, (2 * (J) + 5) % 7, (((J) + 1) & 1) * 2)                \
            HD(r0 - 1, (2 * (J) + 6) % 7, (((J) + 1) & 1) * 2 + 1)            \
            __syncthreads();                                                  \
        }                                                                     \
    }

    for (int t2 = 0; t2 < 2; ++t2) {
        PAIR(0)  PAIR(1)  PAIR(2)  PAIR(3)  PAIR(4)  PAIR(5)  PAIR(6)
        PAIR(7)  PAIR(8)  PAIR(9)  PAIR(10) PAIR(11) PAIR(12) PAIR(13)
    }
#undef PAIR
#undef HD
#undef WPASS

    // deterministic block reduction
    red[tid] = lsum;
    __syncthreads();
    for (int off = 128; off > 0; off >>= 1) {
        if (tid < off) red[tid] += red[tid + off];
        __syncthreads();
    }
    if (tid == 0)
        partials[(blockIdx.z * gridDim.y + blockIdx.y) * gridDim.x + blockIdx.x] = red[0];
}

__global__ __launch_bounds__(256) void k_final(
    const float* __restrict__ partials, int n, float scale, float* __restrict__ out)
{
    __shared__ float red[256];
    float s = 0.f;
    for (int i = threadIdx.x; i < n; i += 256) s += partials[i];
    red[threadIdx.x] = s;
    __syncthreads();
    for (int off = 128; off > 0; off >>= 1) {
        if (threadIdx.x < off) red[threadIdx.x] += red[threadIdx.x + off];
        __syncthreads();
    }
    if (threadIdx.x == 0) out[0] = red[0] * scale;
}

extern "C" void kernel_launch(void* const* d_in, const int* in_sizes, int n_in,
                              void* d_out, int out_size, void* d_ws, size_t ws_size,
                              hipStream_t stream)
{
    const float* img1 = (const float*)d_in[0];
    const float* img2 = (const float*)d_in[1];
    float* out = (float*)d_out;
    float* partials = (float*)d_ws;

    Gw gw;
    {
        double gs[7], sum = 0.0;
        for (int i = 0; i < 7; ++i) { double x = i - 3; gs[i] = exp(-x * x / 4.5); sum += gs[i]; }
        for (int i = 0; i < 7; ++i) gw.g[i] = (float)(gs[i] / sum);
    }

    dim3 grid(256 / TW, 256 / TH, NB * NCH);   // 8 x 16 x 8 = 1024 blocks
    k_fused<<<grid, dim3(256), 0, stream>>>(img1, img2, gw, partials);
    k_final<<<dim3(1), dim3(256), 0, stream>>>(
        partials, (256 / TW) * (256 / TH) * NB * NCH, (float)(1.0 / 20971520.0), out);
}

// Round 23
// 151.519 us; speedup vs baseline: 36.4243x; 36.4243x over previous
//
#include <hip/hip_runtime.h>
#include <math.h>

#define HW 65536
#define DD 160
#define NB 2
#define DCH 40
#define NSL (DCH + 6)   // 46 marched slices per chunk incl. halo
#define NCH 4
#define TW 32
#define TH 16
#define PH 23           // h-pitch (odd -> 2-way LDS access, free)

#define SSIM_C1 1e-4f
#define SSIM_C2 9e-4f

typedef float f32x2 __attribute__((ext_vector_type(2)));

struct Gw { float g[7]; };

static __device__ __forceinline__ f32x2 s2(float v) { f32x2 r; r.x = v; r.y = v; return r; }

// Fused SSIM3D FINAL (== v15/v21 champion, 151.6us): depth-2 ping-pong
// register prefetch (slice r consumes buf[r&1] loaded at r-2, refills with
// r+2; 14-phase compile-time unroll; raw-load issue sites; multiplier masking
// at consumption) + u/v field algebra (u=x+y, v=x-y -> 4 conv fields
// {u,v,u^2,v^2} in two packed f32x2 planes). 256-thread blocks, 1024 blocks,
// double-buffered transposed LDS planes, ONE __syncthreads per slice.
// The ~100us latency/barrier floor survived attacks on block size, barrier
// density (R12/R16/R22), pipeline depth (R13/R16), wave autonomy (R9/R18/R19),
// and algebra (R10-R15); this is the plateau configuration at HIP source level.
__global__ __launch_bounds__(256, 2) void k_fused(
    const float* __restrict__ img1, const float* __restrict__ img2,
    Gw gw, float* __restrict__ partials)
{
    __shared__ f32x2 pUV[2][TW][PH];   // (conv_w u, conv_w v)
    __shared__ f32x2 pSQ[2][TW][PH];   // (conv_w u^2, conv_w v^2)
    __shared__ float red[256];

    const int tid = threadIdx.x;
    const int nb = blockIdx.z >> 2;
    const int o0 = (blockIdx.z & 3) * DCH;
    const int h0 = blockIdx.y * TH;
    const int w0 = blockIdx.x * TW;
    const float* i1 = img1 + (size_t)nb * DD * HW;
    const float* i2 = img2 + (size_t)nb * DD * HW;

    // ---- W-thread geometry (tid < 176): row hh (0..21), 4 outputs at wb ----
    const bool wth = (tid < 176);
    const int hh = tid >> 3;
    const int wb = (tid & 7) * 4;
    const int gh = h0 - 3 + hh;
    const int gwb = w0 - 3 + wb;
    const bool ghv = wth && ((unsigned)gh < 256u);
    const int ghc = gh < 0 ? 0 : (gh > 255 ? 255 : gh);
    int coff[10];
    float mx[10];
#pragma unroll
    for (int i = 0; i < 10; ++i) {
        int gwi = gwb + i;
        int gc = gwi < 0 ? 0 : (gwi > 255 ? 255 : gwi);
        coff[i] = ghc * 256 + gc;                      // always-in-bounds address
        mx[i] = (ghv && gwi == gc) ? 1.f : 0.f;        // zero-pad multiplier
    }

    // ---- H/D geometry: all 256 threads, 2 output rows each ----
    const int wcol = tid & 31;
    const int hb = (tid >> 5) * 2;   // 0..14

    f32x2 ringUV[2][7] = {};
    f32x2 ringSQ[2][7] = {};
    float lsum = 0.f;
    f32x2 cA[10], cB[10];   // depth-2 ping-pong slice buffers (raw x,y)

    // raw slice loader: 20 independent loads, NO dependent VALU at issue site
    auto LOADTO = [&](f32x2 (&buf)[10], int s) {
        const float* p1 = i1 + (size_t)s * HW;
        const float* p2 = i2 + (size_t)s * HW;
#pragma unroll
        for (int i = 0; i < 10; ++i) buf[i].x = p1[coff[i]];
#pragma unroll
        for (int i = 0; i < 10; ++i) buf[i].y = p2[coff[i]];
    };

    // prologue: slice r=0 -> cA, slice r=1 -> cB (skipped if out of range;
    // W-pass is also skipped for those r, so buffer contents don't matter)
    {
        const int s0 = o0 - 3;
        if (s0 >= 0 && wth) LOADTO(cA, s0);
        const int s1 = o0 - 2;
        if (s1 >= 0 && wth) LOADTO(cB, s1);
    }

#define PHASE(Q, CUR)                                                         \
    {                                                                         \
        const int r = 14 * t2 + (Q);                                          \
        if (r <= NSL) {                                                       \
            const int scur = o0 - 3 + r;                                      \
            const bool wv = (r < NSL) && (scur >= 0) && (scur < DD);          \
            /* 1) W-pass consumes CUR (loaded 2 iterations ago) */            \
            if (wv && wth) {                                                  \
                f32x2 aUV[4] = {};                                            \
                f32x2 aSQ[4] = {};                                            \
                _Pragma("unroll")                                             \
                for (int i = 0; i < 10; ++i) {                                \
                    f32x2 uv;                                                 \
                    uv.x = CUR[i].x + CUR[i].y;                               \
                    uv.y = CUR[i].x - CUR[i].y;                               \
                    uv = uv * s2(mx[i]);                                      \
                    const f32x2 sq = uv * uv;                                 \
                    _Pragma("unroll")                                         \
                    for (int o = 0; o < 4; ++o) {                             \
                        const int k = i - o;                                  \
                        if (k >= 0 && k < 7) {                                \
                            const float gk = gw.g[k];                         \
                            aUV[o] += s2(gk) * uv;                            \
                            aSQ[o] += s2(gk) * sq;                            \
                        }                                                     \
                    }                                                         \
                }                                                             \
                _Pragma("unroll")                                             \
                for (int o = 0; o < 4; ++o) {                                 \
                    pUV[(Q) & 1][wb + o][hh] = aUV[o];                        \
                    pSQ[(Q) & 1][wb + o][hh] = aSQ[o];                        \
                }                                                             \
            }                                                                 \
            /* 2) depth-2 prefetch: slice r+2 into CUR (consumed at r+2) */   \
            {                                                                 \
                const int sn2 = scur + 2;                                     \
                if ((r + 2 < NSL) && (sn2 >= 0) && (sn2 < DD) && wth)         \
                    LOADTO(CUR, sn2);                                         \
            }                                                                 \
            /* 3) H-pass + D-ring + SSIM for rp = r-1 (other plane buffer) */ \
            if (r >= 1) {                                                     \
                const int rp = r - 1;                                         \
                const int sp = o0 - 3 + rp;                                   \
                if (sp >= 0 && sp < DD) {                                     \
                    f32x2 vU[8], vS[8];                                       \
                    _Pragma("unroll")                                         \
                    for (int i = 0; i < 8; ++i) {                             \
                        vU[i] = pUV[((Q) + 1) & 1][wcol][hb + i];             \
                        vS[i] = pSQ[((Q) + 1) & 1][wcol][hb + i];             \
                    }                                                         \
                    _Pragma("unroll")                                         \
                    for (int o = 0; o < 2; ++o) {                             \
                        f32x2 aU = s2(0.f), aS = s2(0.f);                     \
                        _Pragma("unroll")                                     \
                        for (int k = 0; k < 7; ++k) {                         \
                            const float gk = gw.g[k];                         \
                            aU += s2(gk) * vU[o + k];                         \
                            aS += s2(gk) * vS[o + k];                         \
                        }                                                     \
                        ringUV[o][((Q) + 6) % 7] = aU;                        \
                        ringSQ[o][((Q) + 6) % 7] = aS;                        \
                    }                                                         \
                } else {                                                      \
                    _Pragma("unroll")                                         \
                    for (int o = 0; o < 2; ++o) {                             \
                        ringUV[o][((Q) + 6) % 7] = s2(0.f);                   \
                        ringSQ[o][((Q) + 6) % 7] = s2(0.f);                   \
                    }                                                         \
                }                                                             \
                if (r >= 7) {                                                 \
                    _Pragma("unroll")                                         \
                    for (int o = 0; o < 2; ++o) {                             \
                        f32x2 cU = s2(0.f), cS = s2(0.f);                     \
                        _Pragma("unroll")                                     \
                        for (int k = 0; k < 7; ++k) {                         \
                            const float gk = gw.g[k];                         \
                            const int pp = (((Q) + 6) % 7 + 1 + k) % 7;       \
                            cU += s2(gk) * ringUV[o][pp];                     \
                            cS += s2(gk) * ringSQ[o][pp];                     \
                        }                                                     \
                        /* A=conv(u), B=conv(v), P=conv(u^2), Q=conv(v^2) */  \
                        const f32x2 ab2 = cU * cU;                            \
                        const float sAB = ab2.x + ab2.y;                      \
                        const float dAB = ab2.x - ab2.y;                      \
                        const float sPQ = cS.x + cS.y;                        \
                        const float dPQ = cS.x - cS.y;                        \
                        const float num1 = 0.5f * dAB + SSIM_C1;              \
                        const float num2 = 0.5f * (dPQ - dAB) + SSIM_C2;      \
                        const float den1 = 0.5f * sAB + SSIM_C1;              \
                        const float den2 = 0.5f * (sPQ - sAB) + SSIM_C2;      \
                        lsum += (num1 * num2) *                               \
                                __builtin_amdgcn_rcpf(den1 * den2);           \
                    }                                                         \
                }                                                             \
            }                                                                 \
            __syncthreads();                                                  \
        }                                                                     \
    }

    for (int t2 = 0; t2 < 4; ++t2) {
        PHASE(0, cA)  PHASE(1, cB)  PHASE(2, cA)  PHASE(3, cB)
        PHASE(4, cA)  PHASE(5, cB)  PHASE(6, cA)  PHASE(7, cB)
        PHASE(8, cA)  PHASE(9, cB)  PHASE(10, cA) PHASE(11, cB)
        PHASE(12, cA) PHASE(13, cB)
    }
#undef PHASE

    // deterministic block reduction
    red[tid] = lsum;
    __syncthreads();
    for (int off = 128; off > 0; off >>= 1) {
        if (tid < off) red[tid] += red[tid + off];
        __syncthreads();
    }
    if (tid == 0)
        partials[(blockIdx.z * gridDim.y + blockIdx.y) * gridDim.x + blockIdx.x] = red[0];
}

__global__ __launch_bounds__(256) void k_final(
    const float* __restrict__ partials, int n, float scale, float* __restrict__ out)
{
    __shared__ float red[256];
    float s = 0.f;
    for (int i = threadIdx.x; i < n; i += 256) s += partials[i];
    red[threadIdx.x] = s;
    __syncthreads();
    for (int off = 128; off > 0; off >>= 1) {
        if (threadIdx.x < off) red[threadIdx.x] += red[threadIdx.x + off];
        __syncthreads();
    }
    if (threadIdx.x == 0) out[0] = red[0] * scale;
}

extern "C" void kernel_launch(void* const* d_in, const int* in_sizes, int n_in,
                              void* d_out, int out_size, void* d_ws, size_t ws_size,
                              hipStream_t stream)
{
    const float* img1 = (const float*)d_in[0];
    const float* img2 = (const float*)d_in[1];
    float* out = (float*)d_out;
    float* partials = (float*)d_ws;

    Gw gw;
    {
        double gs[7], sum = 0.0;
        for (int i = 0; i < 7; ++i) { double x = i - 3; gs[i] = exp(-x * x / 4.5); sum += gs[i]; }
        for (int i = 0; i < 7; ++i) gw.g[i] = (float)(gs[i] / sum);
    }

    dim3 grid(256 / TW, 256 / TH, NB * NCH);   // 8 x 16 x 8 = 1024 blocks
    k_fused<<<grid, dim3(256), 0, stream>>>(img1, img2, gw, partials);
    k_final<<<dim3(1), dim3(256), 0, stream>>>(
        partials, (256 / TW) * (256 / TH) * NB * NCH, (float)(1.0 / 20971520.0), out);
}